// Round 3
// baseline (140.644 us; speedup 1.0000x reference)
//
#include <hip/hip_runtime.h>

#define MAXC    1000
#define DSUB    16          // dims per block slice
#define LSTR    17          // padded class stride in LDS ints
#define THREADS 1024
#define NCHUNK  32
#define FIXS    1048576.0f  // 2^20 fixed-point scale
#define INVFIXS (1.0f / 1048576.0f)

// ---------------------------------------------------------------------------
// Kernel 1: segment-sum scatter, LDS-privatized in int32 fixed point.
// Block (chunkIdx, dimGroup) owns a DSUB=16-dim slice of all C classes.
// LDS = 68 KB sums + 4 KB counts -> 2 blocks/CU (32 waves/CU).
// 2-stage software pipeline: prefetch next 4-sample batch before the
// current batch's 16 LDS atomics.
// MODE 0: flush to per-chunk partial buffers with plain stores (no atomics).
// MODE 1: flush with native global int atomics (small-ws fallback).
// ---------------------------------------------------------------------------
template <int MODE>
__global__ __launch_bounds__(THREADS, 8) void scatter_kernel(
    const float* __restrict__ x, const int* __restrict__ l,
    float* __restrict__ part, float* __restrict__ cnt_part,
    int* __restrict__ sums_i, int* __restrict__ cnt_i,
    int B, int D, int C, int chunk)
{
    __shared__ int lsum[MAXC * LSTR];
    __shared__ int lcnt[MAXC];

    for (int i = threadIdx.x; i < MAXC * LSTR; i += THREADS) lsum[i] = 0;
    for (int i = threadIdx.x; i < MAXC; i += THREADS) lcnt[i] = 0;
    __syncthreads();

    const bool doCount = (blockIdx.y == 0);
    const int dbase = blockIdx.y * DSUB;
    const int q    = threadIdx.x & 3;        // dim-quad within the 16-dim slice
    const int srel = threadIdx.x >> 2;       // 0..255
    const int STEP = THREADS >> 2;           // 256 samples in flight per step
    const int DV   = D >> 2;                 // row stride in float4
    const int qb   = (dbase >> 2) + q;

    const float4* __restrict__ x4 = (const float4*)x;

    const int s0 = blockIdx.x * chunk;
    const int s1 = min(B, s0 + chunk);

#define ACC4(cc, vv)                                                   \
    {                                                                  \
        const int b_ = (cc) * LSTR + (q << 2);                         \
        atomicAdd(&lsum[b_ + 0], __float2int_rn((vv).x * FIXS));       \
        atomicAdd(&lsum[b_ + 1], __float2int_rn((vv).y * FIXS));       \
        atomicAdd(&lsum[b_ + 2], __float2int_rn((vv).z * FIXS));       \
        atomicAdd(&lsum[b_ + 3], __float2int_rn((vv).w * FIXS));       \
    }

    int s = s0 + srel;
    if (s + 3 * STEP < s1) {
        int c0 = l[s];
        int c1 = l[s + STEP];
        int c2 = l[s + 2 * STEP];
        int c3 = l[s + 3 * STEP];
        float4 v0 = x4[(size_t)s * DV + qb];
        float4 v1 = x4[(size_t)(s + STEP) * DV + qb];
        float4 v2 = x4[(size_t)(s + 2 * STEP) * DV + qb];
        float4 v3 = x4[(size_t)(s + 3 * STEP) * DV + qb];
        int sn = s + 4 * STEP;
        for (; sn + 3 * STEP < s1; sn += 4 * STEP) {
            // prefetch next batch before current batch's atomics
            int n0 = l[sn];
            int n1 = l[sn + STEP];
            int n2 = l[sn + 2 * STEP];
            int n3 = l[sn + 3 * STEP];
            float4 w0 = x4[(size_t)sn * DV + qb];
            float4 w1 = x4[(size_t)(sn + STEP) * DV + qb];
            float4 w2 = x4[(size_t)(sn + 2 * STEP) * DV + qb];
            float4 w3 = x4[(size_t)(sn + 3 * STEP) * DV + qb];
            ACC4(c0, v0); ACC4(c1, v1); ACC4(c2, v2); ACC4(c3, v3);
            if (doCount && q == 0) {
                atomicAdd(&lcnt[c0], 1);
                atomicAdd(&lcnt[c1], 1);
                atomicAdd(&lcnt[c2], 1);
                atomicAdd(&lcnt[c3], 1);
            }
            c0 = n0; c1 = n1; c2 = n2; c3 = n3;
            v0 = w0; v1 = w1; v2 = w2; v3 = w3;
        }
        ACC4(c0, v0); ACC4(c1, v1); ACC4(c2, v2); ACC4(c3, v3);
        if (doCount && q == 0) {
            atomicAdd(&lcnt[c0], 1);
            atomicAdd(&lcnt[c1], 1);
            atomicAdd(&lcnt[c2], 1);
            atomicAdd(&lcnt[c3], 1);
        }
        s = sn;
    }
    for (; s < s1; s += STEP) {
        int c = l[s];
        float4 v = x4[(size_t)s * DV + qb];
        ACC4(c, v);
        if (doCount && q == 0) atomicAdd(&lcnt[c], 1);
    }
    __syncthreads();

    if (MODE == 0) {
        float* myp = part + (size_t)blockIdx.x * C * D + dbase;
        for (int i = threadIdx.x; i < C * DSUB; i += THREADS) {
            const int c = i >> 4, d = i & (DSUB - 1);
            myp[(size_t)c * D + d] = (float)lsum[c * LSTR + d] * INVFIXS;
        }
        if (doCount)
            for (int i = threadIdx.x; i < C; i += THREADS)
                cnt_part[(size_t)blockIdx.x * C + i] = (float)lcnt[i];
    } else {
        for (int i = threadIdx.x; i < C * DSUB; i += THREADS) {
            const int c = i >> 4, d = i & (DSUB - 1);
            const int v = lsum[c * LSTR + d];
            if (v) atomicAdd(&sums_i[(size_t)c * D + dbase + d], v);
        }
        if (doCount)
            for (int i = threadIdx.x; i < C; i += THREADS) {
                const int v = lcnt[i];
                if (v) atomicAdd(&cnt_i[i], v);
            }
    }
#undef ACC4
}

// ---------------------------------------------------------------------------
// block-wide sum over 256 threads (4 waves); result broadcast to all threads
// ---------------------------------------------------------------------------
__device__ __forceinline__ float block_reduce_sum_256(float v, float* sbuf) {
    #pragma unroll
    for (int o = 32; o > 0; o >>= 1) v += __shfl_down(v, o, 64);
    __syncthreads();                 // protect sbuf across repeated calls
    if ((threadIdx.x & 63) == 0) sbuf[threadIdx.x >> 6] = v;
    __syncthreads();
    return sbuf[0] + sbuf[1] + sbuf[2] + sbuf[3];
}

// ---------------------------------------------------------------------------
// Kernel 2: reduce partials + per-class momentum update + renorm + sq dist.
// One block (256 threads == D) per class.
// ---------------------------------------------------------------------------
template <int MODE>
__global__ __launch_bounds__(256) void update_kernel(
    const float* __restrict__ part, const float* __restrict__ cnt_part,
    const int* __restrict__ sums_i, const int* __restrict__ cnt_i,
    const float* __restrict__ cimg, const float* __restrict__ cskt,
    float* __restrict__ sq_out, float* __restrict__ pres_out, int C, int D)
{
    __shared__ float sbuf[4];
    __shared__ float cshare;
    const int c = blockIdx.x;
    const int t = threadIdx.x;

    float ssum, cnt;
    if (MODE == 0) {
        ssum = 0.f;
        const float* pc = part + (size_t)c * D + t;
        #pragma unroll
        for (int k = 0; k < NCHUNK; ++k) ssum += pc[(size_t)k * C * D];
        if (t < NCHUNK) {
            float cv = cnt_part[(size_t)t * C + c];
            #pragma unroll
            for (int o = NCHUNK / 2; o > 0; o >>= 1) cv += __shfl_down(cv, o, NCHUNK);
            if (t == 0) cshare = cv;
        }
        __syncthreads();
        cnt = cshare;
    } else {
        ssum = (float)sums_i[(size_t)c * D + t] * INVFIXS;
        if (t == 0) cshare = (float)cnt_i[c];
        __syncthreads();
        cnt = cshare;
    }

    const bool present = cnt > 0.5f;
    const size_t idx = (size_t)c * D + t;
    const float ci = cimg[idx];
    const float cs = cskt[idx];
    const float mean = ssum / fmaxf(cnt, 1.f);
    const float upd = ci * 0.9f + mean * 0.1f;
    const float n2 = block_reduce_sum_256(upd * upd, sbuf);
    const float inv = 1.0f / sqrtf(n2);
    const float newv = present ? upd * inv : ci;
    const float df = newv - cs;
    const float sq = block_reduce_sum_256(df * df, sbuf);
    if (t == 0) {
        sq_out[c]   = present ? sq : 0.f;
        pres_out[c] = present ? 1.f : 0.f;
    }
}

// ---------------------------------------------------------------------------
// Kernel 3: final reduction over classes -> scalar loss
// ---------------------------------------------------------------------------
__global__ __launch_bounds__(256) void finalize_kernel(
    const float* __restrict__ sq, const float* __restrict__ pres,
    float* __restrict__ out, int C)
{
    __shared__ float sbuf[4];
    float ls = 0.f, np = 0.f;
    for (int i = threadIdx.x; i < C; i += 256) {
        ls += sq[i];
        np += pres[i];
    }
    ls = block_reduce_sum_256(ls, sbuf);
    np = block_reduce_sum_256(np, sbuf);
    if (threadIdx.x == 0) out[0] = ls / fmaxf(np, 1.f);
}

extern "C" void kernel_launch(void* const* d_in, const int* in_sizes, int n_in,
                              void* d_out, int out_size, void* d_ws, size_t ws_size,
                              hipStream_t stream) {
    const float* x    = (const float*)d_in[0];
    const int*   l    = (const int*)d_in[1];
    const float* cimg = (const float*)d_in[2];
    const float* cskt = (const float*)d_in[3];

    const int B = in_sizes[1];
    const int D = in_sizes[0] / B;     // 256
    const int C = in_sizes[2] / D;     // 1000

    const size_t partElems = (size_t)NCHUNK * C * D;     // 8.19M floats
    const size_t cntElems  = (size_t)NCHUNK * C;
    const size_t need0 = (partElems + cntElems + 2 * (size_t)C) * sizeof(float);

    const int chunk = (B + NCHUNK - 1) / NCHUNK;
    dim3 grid(NCHUNK, D / DSUB);       // 32 x 16 = 512 blocks (2/CU)

    if (ws_size >= need0) {
        // partials path: zero global atomics, no memset needed
        float* part     = (float*)d_ws;
        float* cnt_part = part + partElems;
        float* sq       = cnt_part + cntElems;
        float* pres     = sq + C;
        scatter_kernel<0><<<grid, THREADS, 0, stream>>>(
            x, l, part, cnt_part, nullptr, nullptr, B, D, C, chunk);
        update_kernel<0><<<C, 256, 0, stream>>>(
            part, cnt_part, nullptr, nullptr, cimg, cskt, sq, pres, C, D);
        finalize_kernel<<<1, 256, 0, stream>>>(sq, pres, (float*)d_out, C);
    } else {
        // fallback: native int32 global atomics
        int*   sums_i = (int*)d_ws;
        int*   cnt_i  = sums_i + (size_t)C * D;
        float* sq     = (float*)(cnt_i + C);
        float* pres   = sq + C;
        hipMemsetAsync(d_ws, 0, sizeof(int) * ((size_t)C * D + C), stream);
        scatter_kernel<1><<<grid, THREADS, 0, stream>>>(
            x, l, nullptr, nullptr, sums_i, cnt_i, B, D, C, chunk);
        update_kernel<1><<<C, 256, 0, stream>>>(
            nullptr, nullptr, sums_i, cnt_i, cimg, cskt, sq, pres, C, D);
        finalize_kernel<<<1, 256, 0, stream>>>(sq, pres, (float*)d_out, C);
    }
}